// Round 5
// baseline (2754.209 us; speedup 1.0000x reference)
//
#include <hip/hip_runtime.h>
#include <hip/hip_bf16.h>
#include <math.h>

// ---------- types ----------
typedef __bf16 bf16x8 __attribute__((ext_vector_type(8)));
typedef float  f32x4  __attribute__((ext_vector_type(4)));
typedef unsigned short us8 __attribute__((ext_vector_type(8)));
typedef unsigned short us4 __attribute__((ext_vector_type(4)));
typedef unsigned short ush;

__device__ __forceinline__ unsigned short f2bf(float x) {
  unsigned int u = __float_as_uint(x);
  u += 0x7FFFu + ((u >> 16) & 1u);          // RNE
  return (unsigned short)(u >> 16);
}
__device__ __forceinline__ float bf2f(unsigned short v) {
  return __uint_as_float(((unsigned int)v) << 16);
}
// tanh-form GELU via exp2/rcp: x / (1 + 2^(-x*(k1 + k2*x^2)))
// k1 = 2*0.7978845608*log2(e) = 2.30220897, k2 = k1*0.044715 = 0.10294325
// max |diff vs erf-gelu| ~1e-3, harmless vs threshold
__device__ __forceinline__ float gelu_t(float x) {
  float s = 2.30220897f + 0.10294325f * x * x;
  float t = __builtin_amdgcn_exp2f(-x * s);
  return x * __builtin_amdgcn_rcpf(1.0f + t);
}

// Problem constants: B=32, V=4, P=784, D=768; rows n = bp*4+v, bp=b*784+p
// NROW = 100352 = 392*256
//
// BLOCKED A-LAYOUT: every GEMM A-operand is stored as contiguous 32 KB
// staging tiles: tile(by, kstep) holds rows r=0..255, k-elems kstep*64..+63,
// at in-tile ush offset r*64 + ((sub16 ^ (r&7)) << 3) + (k&7), sub16=(k>>3)&7.
// Byte-identical to the GEMM's swizzled LDS image -> A-stage is a linear
// lane-contiguous global_load_lds copy; ds_read side unchanged.

// ---------- f32 -> bf16 convert (weights) ----------
__global__ __launch_bounds__(256) void conv_f32_bf16(const float* __restrict__ s,
                                                     unsigned short* __restrict__ d, int n4) {
  int i = blockIdx.x * 256 + threadIdx.x;
  if (i >= n4) return;
  f32x4 f = ((const f32x4*)s)[i];
  us4 u;
  u[0] = f2bf(f[0]); u[1] = f2bf(f[1]); u[2] = f2bf(f[2]); u[3] = f2bf(f[3]);
  ((us4*)d)[i] = u;
}

// ---------- LayerNorm: NT-read permuted fp32 row, write blocked-A bf16 ----------
__global__ __launch_bounds__(256) void ln_kernel(const float* __restrict__ src,
                                                 const float* __restrict__ w,
                                                 const float* __restrict__ b,
                                                 unsigned short* __restrict__ dst) {
  const int wv = threadIdx.x >> 6;
  const int lane = threadIdx.x & 63;
  const int n = blockIdx.x * 4 + wv;            // token row 0..100351
  const int bp = n >> 2, v = n & 3;
  const int bb = bp / 784, p = bp - bb * 784;
  const float* row = src + ((size_t)bb * 3136 + (size_t)v * 784 + p) * 768;
  f32x4 x0 = __builtin_nontemporal_load((const f32x4*)row + lane);
  f32x4 x1 = __builtin_nontemporal_load((const f32x4*)row + lane + 64);
  f32x4 x2 = __builtin_nontemporal_load((const f32x4*)row + lane + 128);
  float s  = x0[0] + x0[1] + x0[2] + x0[3] + x1[0] + x1[1] + x1[2] + x1[3]
           + x2[0] + x2[1] + x2[2] + x2[3];
  float ss = x0[0]*x0[0] + x0[1]*x0[1] + x0[2]*x0[2] + x0[3]*x0[3]
           + x1[0]*x1[0] + x1[1]*x1[1] + x1[2]*x1[2] + x1[3]*x1[3]
           + x2[0]*x2[0] + x2[1]*x2[1] + x2[2]*x2[2] + x2[3]*x2[3];
  #pragma unroll
  for (int off = 32; off > 0; off >>= 1) {
    s  += __shfl_xor(s,  off, 64);
    ss += __shfl_xor(ss, off, 64);
  }
  const float mu   = s * (1.0f / 768.0f);
  const float rstd = rsqrtf(ss * (1.0f / 768.0f) - mu * mu + 1e-5f);
  // blocked-A store: k = (lane + seg*64)*4 ; kstep=(lane>>4)+seg*4 ;
  // sub16=(lane>>1)&7 ; k&7=(lane&1)*4 ; r = n&255
  const int r = n & 255;
  unsigned short* bb2 = dst + (((size_t)(n >> 8) * 12) << 14) + r * 64
                      + ((((lane >> 1) & 7) ^ (r & 7)) << 3) + ((lane & 1) << 2);
  #pragma unroll
  for (int seg = 0; seg < 3; ++seg) {
    f32x4 xs = (seg == 0) ? x0 : (seg == 1) ? x1 : x2;
    f32x4 w4 = ((const f32x4*)w)[lane + seg * 64];
    f32x4 b4 = ((const f32x4*)b)[lane + seg * 64];
    us4 u;
    u[0] = f2bf((xs[0] - mu) * rstd * w4[0] + b4[0]);
    u[1] = f2bf((xs[1] - mu) * rstd * w4[1] + b4[1]);
    u[2] = f2bf((xs[2] - mu) * rstd * w4[2] + b4[2]);
    u[3] = f2bf((xs[3] - mu) * rstd * w4[3] + b4[3]);
    *(us4*)(bb2 + (((size_t)((lane >> 4) + seg * 4)) << 14)) = u;
  }
}

// =====================================================================
// GEMM: C = A(blocked bf16, MxK) * B(bf16, NxK)^T + epilogue
// 256x256 tile, BK=64, 8 waves (2M x 4N), 16x16x32 bf16 MFMA,
// 8-phase counted-vmcnt schedule, XOR-swizzled LDS (conflict-free b128).
// Tile order: per XCD, bx in groups of GB with by fastest -> B working set
// GB*393KB stays L2-resident; A re-read gx/GB times from L3 (wh L3-hot).
// Output streams: non-temporal (EPI 0/2/3) to avoid evicting A/B caches.
// =====================================================================

#define BARX() do { asm volatile("" ::: "memory"); \
                    __builtin_amdgcn_s_barrier();  \
                    asm volatile("" ::: "memory"); } while (0)
#define WAITVM(N) asm volatile("s_waitcnt vmcnt(" #N ")" ::: "memory")

// stage one 128-row half (16 KiB) of blocked A tile TT (linear copy)
#define STAGE_A(HALF, TT) do {                                                \
  _Pragma("unroll")                                                           \
  for (int _j = 0; _j < 2; ++_j) {                                            \
    const int _ob = ((HALF) << 13) + (w << 10) + (_j << 9);                   \
    __builtin_amdgcn_global_load_lds(                                         \
        (const __attribute__((address_space(1))) void*)(                      \
            gAt + (((size_t)(TT)) << 14) + _ob + lnoff8),                     \
        (__attribute__((address_space(3))) void*)(                            \
            smem + ((((TT) & 1)) << 15) + _ob), 16, 0, 0);                    \
  }                                                                           \
} while (0)

// stage one 128-row half (16 KiB) of B for K-step TT (pre-swizzled source)
#define STAGE_B(HALF, TT) do {                                                \
  const int _l0 = ((((TT) & 1)) << 15) + 16384 + ((HALF) << 13) + (w << 9);   \
  const ush* _g = gB + (size_t)(((HALF) << 7) + (w << 3)) * K                 \
                + (((size_t)(TT)) << 6);                                      \
  __builtin_amdgcn_global_load_lds(                                           \
      (const __attribute__((address_space(1))) void*)_g,                      \
      (__attribute__((address_space(3))) void*)(smem + _l0), 16, 0, 0);       \
  __builtin_amdgcn_global_load_lds(                                           \
      (const __attribute__((address_space(1))) void*)(_g + ((size_t)K << 6)), \
      (__attribute__((address_space(3))) void*)(smem + _l0 + 4096), 16, 0, 0);\
} while (0)

#define LDA(HM) do {                                                          \
  _Pragma("unroll")                                                           \
  for (int mi4 = 0; mi4 < 4; ++mi4) {                                         \
    const int m = wm * 64 + (HM) * 128 + mi4 * 16 + l16;                      \
    _Pragma("unroll")                                                         \
    for (int kk = 0; kk < 2; ++kk) {                                          \
      const int q = kk * 4 + quad;                                            \
      af[mi4][kk] = *(const bf16x8*)(smem + aofs + m * 64 + ((q ^ (m & 7)) << 3)); \
    }                                                                         \
  }                                                                           \
} while (0)

#define LDB(HN, BF) do {                                                      \
  _Pragma("unroll")                                                           \
  for (int ni2 = 0; ni2 < 2; ++ni2) {                                         \
    const int n = wn * 32 + (HN) * 128 + ni2 * 16 + l16;                      \
    _Pragma("unroll")                                                         \
    for (int kk = 0; kk < 2; ++kk) {                                          \
      const int q = kk * 4 + quad;                                            \
      BF[ni2][kk] = *(const bf16x8*)(smem + bofs + n * 64 + ((q ^ (n & 7)) << 3)); \
    }                                                                         \
  }                                                                           \
} while (0)

#define MFMAC(HM, HN, BF) do {                                                \
  __builtin_amdgcn_s_setprio(1);                                              \
  _Pragma("unroll")                                                           \
  for (int mi4 = 0; mi4 < 4; ++mi4)                                           \
    _Pragma("unroll")                                                         \
    for (int ni2 = 0; ni2 < 2; ++ni2)                                         \
      _Pragma("unroll")                                                       \
      for (int kk = 0; kk < 2; ++kk)                                          \
        acc[(HM)*4 + mi4][(HN)*2 + ni2] = __builtin_amdgcn_mfma_f32_16x16x32_bf16( \
            af[mi4][kk], BF[ni2][kk], acc[(HM)*4 + mi4][(HN)*2 + ni2], 0, 0, 0); \
  __builtin_amdgcn_s_setprio(0);                                              \
} while (0)

// EPI: 0 = +bias -> qkv bf16 [bp][seg][h][v][96]            (NT store)
//      1 = +bias +aux(NT) residual -> fp32 unfolded          (cached store)
//      2 = +bias, gelu -> bf16 blocked-A layout (NT=48)      (NT store)
//      3 = +bias +aux residual -> fp32 unfolded              (NT store)
template <int K, int EPI>
__global__ __launch_bounds__(512, 2) void gemm256(const ush* __restrict__ A,
                                                  const ush* __restrict__ Bm,
                                                  const float* __restrict__ bias,
                                                  void* __restrict__ outp,
                                                  const float* __restrict__ aux,
                                                  int N, int GB) {
  __shared__ __attribute__((aligned(16))) ush smem[65536];   // 128 KiB
  constexpr int NT = K / 64;
  const int tid  = threadIdx.x;
  const int w    = tid >> 6;
  const int lane = tid & 63;
  const int quad = lane >> 4;
  const int l16  = lane & 15;
  const int wm   = w >> 2;        // 0..1
  const int wn   = w & 3;         // 0..3

  // XCD-aware GB-snake remap: each XCD owns a 49-panel by-band; within it,
  // bx advances in groups of GB with by fastest (gx % GB == 0 required).
  const int gx   = gridDim.x;
  const int flat = blockIdx.y * gx + blockIdx.x;
  const int xcd  = flat & 7;
  const int p    = flat >> 3;          // [0, gx*49)
  const int gsz  = GB * 49;
  const int g    = p / gsz;
  const int r    = p - g * gsz;
  const int byo  = r / GB;
  const int by   = xcd * 49 + byo;
  const int bx   = g * GB + (r - byo * GB);

  // A: blocked-tile base for this row-panel; lane-contiguous 16B pieces
  const ush* gAt   = A + (((size_t)by * NT) << 14);
  const int  lnoff8 = lane << 3;                 // lane*16B in ush

  // B: pre-swizzled per-lane global source (chunk cb loads chunk cb^r8)
  const int r8  = lane >> 3;
  const int cb  = lane & 7;
  const int swo = (cb ^ r8) << 3;
  const ush* gB = Bm + (size_t)(bx * 256 + r8) * K + swo;

  f32x4 acc[8][4];
  #pragma unroll
  for (int i = 0; i < 8; ++i)
    #pragma unroll
    for (int j = 0; j < 4; ++j) {
      f32x4 z = {0.0f, 0.0f, 0.0f, 0.0f};
      acc[i][j] = z;
    }
  bf16x8 af[4][2], bf0[2][2], bf1[2][2];

  // ---- prologue: stage halves A0,B0,A1,B1(t0), A0,B0(t1) ----
  STAGE_A(0, 0); STAGE_B(0, 0); STAGE_A(1, 0);
  STAGE_B(1, 0); STAGE_A(0, 1); STAGE_B(0, 1);
  WAITVM(8);              // A0(0),B0(0) landed (4 newest halves may fly)
  BARX();

  #pragma unroll 2
  for (int t = 0; t < NT; ++t) {
    const int aofs = (t & 1) << 15;
    const int bofs = aofs + 16384;
    // ---- q0: hm=0, hn=0 ----
    LDA(0); LDB(0, bf0);
    if (t <= NT - 2) STAGE_A(1, t + 1);      // A1(t+1) -> other buf
    BARX();
    MFMAC(0, 0, bf0);
    if (t < NT - 1) { WAITVM(6); } else { WAITVM(0); }  // A1(t),B1(t) landed
    BARX();
    // ---- q1: hm=0, hn=1 ----
    LDB(1, bf1);
    if (t <= NT - 2) STAGE_B(1, t + 1);      // B1(t+1) -> other buf
    BARX();
    MFMAC(0, 1, bf1);
    BARX();
    // ---- q2: hm=1, hn=0 ----
    LDA(1);
    if (t <= NT - 3) STAGE_A(0, t + 2);      // A0(t+2) -> this buf (half0 free)
    BARX();
    MFMAC(1, 0, bf0);
    BARX();
    // ---- q3: hm=1, hn=1 (B frags reused, no ds_reads) ----
    if (t <= NT - 3) STAGE_B(0, t + 2);      // B0(t+2) -> this buf (half0 free)
    BARX();
    MFMAC(1, 1, bf1);
    if (t <= NT - 3)      { WAITVM(8); }     // A0,B0(t+1) landed
    else if (t == NT - 2) { WAITVM(4); }
    BARX();
  }

  // ---- epilogue: 4 stages of 64 rows x 256 cols via LDS (stride 260) ----
  float* lsm = (float*)smem;
  #pragma unroll
  for (int s = 0; s < 4; ++s) {
    if (wm == (s & 1)) {
      const int hm = s >> 1;                 // compile-time (s unrolled)
      #pragma unroll
      for (int mi4 = 0; mi4 < 4; ++mi4)
        #pragma unroll
        for (int ni = 0; ni < 4; ++ni) {
          const int col = wn * 32 + (ni >> 1) * 128 + (ni & 1) * 16 + l16;
          #pragma unroll
          for (int r2 = 0; r2 < 4; ++r2) {
            const int row_l = mi4 * 16 + quad * 4 + r2;
            lsm[row_l * 260 + col] = acc[hm * 4 + mi4][ni][r2];
          }
        }
    }
    __syncthreads();
    #pragma unroll
    for (int j = 0; j < 8; ++j) {
      const int cc    = tid + 512 * j;       // 0..4095 = 64 rows x 64 chunks
      const int row_l = cc >> 6;
      const int c4    = (cc & 63) << 2;
      f32x4 vv = *(const f32x4*)&lsm[row_l * 260 + c4];
      const int rr    = by * 256 + s * 64 + row_l;
      const int col_g = bx * 256 + c4;
      f32x4 b4 = *(const f32x4*)&bias[col_g];
      vv += b4;
      if (EPI == 0) {
        const int seg = col_g / 768;
        const int c2  = col_g - seg * 768;
        const int hh  = c2 / 96;
        const int dd  = c2 - hh * 96;
        const int bp = rr >> 2, v = rr & 3;
        us4 u = { f2bf(vv[0]), f2bf(vv[1]), f2bf(vv[2]), f2bf(vv[3]) };
        __builtin_nontemporal_store(u,
            (us4*)((unsigned short*)outp + (size_t)bp * 9216 + seg * 3072 + hh * 384 + v * 96 + dd));
      } else if (EPI == 1 || EPI == 3) {
        const int bp = rr >> 2, v = rr & 3;
        const int bb = bp / 784, p2 = bp - bb * 784;
        const size_t addr = ((size_t)bb * 3136 + (size_t)v * 784 + p2) * 768 + col_g;
        f32x4 a4;
        if (EPI == 1) a4 = __builtin_nontemporal_load((const f32x4*)(aux + addr));
        else          a4 = *(const f32x4*)(aux + addr);
        vv += a4;
        if (EPI == 1) *(f32x4*)((float*)outp + addr) = vv;       // cached: LN2/FFN2 re-read
        else __builtin_nontemporal_store(vv, (f32x4*)((float*)outp + addr));
      } else { // EPI == 2: gelu -> bf16, blocked-A layout (NT=48) for FFN2
        us4 u = { f2bf(gelu_t(vv[0])), f2bf(gelu_t(vv[1])),
                  f2bf(gelu_t(vv[2])), f2bf(gelu_t(vv[3])) };
        const int rb = rr & 255;
        __builtin_nontemporal_store(u,
            (us4*)((unsigned short*)outp
               + (((size_t)(rr >> 8) * 48 + (col_g >> 6)) << 14)
               + rb * 64 + ((((col_g >> 3) & 7) ^ (rb & 7)) << 3) + (col_g & 7)));
      }
    }
    __syncthreads();
  }
}

// ---------- tiny cross-view attention: one thread per (bp, head, vq) ----------
// output: blocked-A layout (NT=12) for the out-proj GEMM
__global__ __launch_bounds__(256) void attn_kernel(const unsigned short* __restrict__ qs,
                                                   unsigned short* __restrict__ o) {
  int idx = blockIdx.x * 256 + threadIdx.x;   // 25088*32 total
  int vq = idx & 3;
  int h  = (idx >> 2) & 7;
  int bp = idx >> 5;
  const unsigned short* qp = qs + (size_t)bp * 9216 + h * 384 + vq * 96;
  const unsigned short* kp = qs + (size_t)bp * 9216 + 3072 + h * 384;
  const unsigned short* vp = qs + (size_t)bp * 9216 + 6144 + h * 384;
  float s0 = 0.f, s1 = 0.f, s2 = 0.f, s3 = 0.f;
  #pragma unroll
  for (int c = 0; c < 96; c += 8) {
    us8 q8 = __builtin_nontemporal_load((const us8*)(qp + c));
    us8 k0 = __builtin_nontemporal_load((const us8*)(kp + c));
    us8 k1 = __builtin_nontemporal_load((const us8*)(kp + 96 + c));
    us8 k2 = __builtin_nontemporal_load((const us8*)(kp + 192 + c));
    us8 k3 = __builtin_nontemporal_load((const us8*)(kp + 288 + c));
    #pragma unroll
    for (int j = 0; j < 8; ++j) {
      float qf = bf2f(q8[j]);
      s0 += qf * bf2f(k0[j]);
      s1 += qf * bf2f(k1[j]);
      s2 += qf * bf2f(k2[j]);
      s3 += qf * bf2f(k3[j]);
    }
  }
  const float scale = 0.10206207261596575f;  // 1/sqrt(96)
  s0 *= scale; s1 *= scale; s2 *= scale; s3 *= scale;
  float m = fmaxf(fmaxf(s0, s1), fmaxf(s2, s3));
  float e0 = __expf(s0 - m), e1 = __expf(s1 - m), e2 = __expf(s2 - m), e3 = __expf(s3 - m);
  float inv = 1.0f / (e0 + e1 + e2 + e3);
  e0 *= inv; e1 *= inv; e2 *= inv; e3 *= inv;
  const int rn = bp * 4 + vq;
  const int rr2 = rn & 255;
  unsigned short* ob = o + (((size_t)(rn >> 8) * 12) << 14) + rr2 * 64;
  #pragma unroll
  for (int c = 0; c < 96; c += 8) {
    us8 v0 = __builtin_nontemporal_load((const us8*)(vp + c));
    us8 v1 = __builtin_nontemporal_load((const us8*)(vp + 96 + c));
    us8 v2 = __builtin_nontemporal_load((const us8*)(vp + 192 + c));
    us8 v3 = __builtin_nontemporal_load((const us8*)(vp + 288 + c));
    us8 r;
    #pragma unroll
    for (int j = 0; j < 8; ++j) {
      float val = e0 * bf2f(v0[j]) + e1 * bf2f(v1[j]) + e2 * bf2f(v2[j]) + e3 * bf2f(v3[j]);
      r[j] = f2bf(val);
    }
    const int k = h * 96 + c;
    *(us8*)(ob + (((size_t)(k >> 6)) << 14) + ((((k >> 3) & 7) ^ (rr2 & 7)) << 3)) = r;
  }
}

// ---------- launch ----------
extern "C" void kernel_launch(void* const* d_in, const int* in_sizes, int n_in,
                              void* d_out, int out_size, void* d_ws, size_t ws_size,
                              hipStream_t stream) {
  const float* x         = (const float*)d_in[0];
  const float* norm1_w   = (const float*)d_in[2];
  const float* norm1_b   = (const float*)d_in[3];
  const float* in_proj_w = (const float*)d_in[4];
  const float* in_proj_b = (const float*)d_in[5];
  const float* out_w     = (const float*)d_in[6];
  const float* out_b     = (const float*)d_in[7];
  const float* norm2_w   = (const float*)d_in[8];
  const float* norm2_b   = (const float*)d_in[9];
  const float* ffn_w1    = (const float*)d_in[10];
  const float* ffn_b1    = (const float*)d_in[11];
  const float* ffn_w2    = (const float*)d_in[12];
  const float* ffn_b2    = (const float*)d_in[13];
  float* out = (float*)d_out;

  char* ws = (char*)d_ws;
  unsigned short* wq = (unsigned short*)ws;                           // 616.6 MB
  unsigned short* wh = (unsigned short*)(ws + 616562688u);            // 154.1 MB
  unsigned short* wB = (unsigned short*)(ws + 616562688u + 154140672u);
  unsigned short* wIn  = wB;
  unsigned short* wOut = wB + 1769472;
  unsigned short* wF1  = wOut + 589824;
  unsigned short* wF2  = wF1 + 2359296;

  conv_f32_bf16<<<(442368 + 255) / 256, 256, 0, stream>>>(in_proj_w, wIn, 442368);
  conv_f32_bf16<<<(147456 + 255) / 256, 256, 0, stream>>>(out_w, wOut, 147456);
  conv_f32_bf16<<<(589824 + 255) / 256, 256, 0, stream>>>(ffn_w1, wF1, 589824);
  conv_f32_bf16<<<(589824 + 255) / 256, 256, 0, stream>>>(ffn_w2, wF2, 589824);

  // LN1: x (NT permuted read) -> wh (blocked-A, NT=12; cached -> L3 for QKV/FFN1)
  ln_kernel<<<25088, 256, 0, stream>>>(x, norm1_w, norm1_b, wh);
  // QKV: wh(100352x768) @ in_proj_w^T -> wq (attention layout, NT store); GB=3
  gemm256<768, 0><<<dim3(9, 392), 512, 0, stream>>>(wh, wIn, in_proj_b, (void*)wq, nullptr, 2304, 3);
  // attention: wq (NT read) -> wh (o, blocked-A NT=12; cached)
  attn_kernel<<<3136, 256, 0, stream>>>(wq, wh);
  // out-proj + residual(x NT): wh @ out_w^T -> d_out fp32 (cached; LN2/FFN2 re-read); GB=3
  gemm256<768, 1><<<dim3(3, 392), 512, 0, stream>>>(wh, wOut, out_b, (void*)out, x, 768, 3);
  // LN2: d_out (permuted read, L3-hot) -> wh (blocked-A, NT=12)
  ln_kernel<<<25088, 256, 0, stream>>>(out, norm2_w, norm2_b, wh);
  // FFN1 + gelu: wh @ ffn_w1^T -> wq (blocked-A, NT=48; NT store); GB=4
  gemm256<768, 2><<<dim3(12, 392), 512, 0, stream>>>(wh, wF1, ffn_b1, (void*)wq, nullptr, 3072, 4);
  // FFN2 + residual(d_out): wq(blocked) @ ffn_w2^T -> d_out fp32 (NT store); GB=3
  gemm256<3072, 3><<<dim3(3, 392), 512, 0, stream>>>(wq, wF2, ffn_b2, (void*)out, out, 768, 3);

  (void)in_sizes; (void)n_in; (void)out_size; (void)ws_size;
}

// Round 6
// 2670.021 us; speedup vs baseline: 1.0315x; 1.0315x over previous
//
#include <hip/hip_runtime.h>
#include <hip/hip_bf16.h>
#include <math.h>

// ---------- types ----------
typedef __bf16 bf16x8 __attribute__((ext_vector_type(8)));
typedef float  f32x4  __attribute__((ext_vector_type(4)));
typedef unsigned short us8 __attribute__((ext_vector_type(8)));
typedef unsigned short us4 __attribute__((ext_vector_type(4)));
typedef unsigned short ush;

__device__ __forceinline__ unsigned short f2bf(float x) {
  unsigned int u = __float_as_uint(x);
  u += 0x7FFFu + ((u >> 16) & 1u);          // RNE
  return (unsigned short)(u >> 16);
}
__device__ __forceinline__ float bf2f(unsigned short v) {
  return __uint_as_float(((unsigned int)v) << 16);
}
// tanh-form GELU via exp2/rcp: x / (1 + 2^(-x*(k1 + k2*x^2)))
// k1 = 2*0.7978845608*log2(e) = 2.30220897, k2 = k1*0.044715 = 0.10294325
// max |diff vs erf-gelu| ~1e-3, harmless vs threshold
__device__ __forceinline__ float gelu_t(float x) {
  float s = 2.30220897f + 0.10294325f * x * x;
  float t = __builtin_amdgcn_exp2f(-x * s);
  return x * __builtin_amdgcn_rcpf(1.0f + t);
}

// Problem constants: B=32, V=4, P=784, D=768; rows n = bp*4+v, bp=b*784+p
// NROW = 100352 = 392*256
//
// BLOCKED A-LAYOUT: every GEMM A-operand is stored as contiguous 32 KB
// staging tiles: tile(by, kstep) holds rows r=0..255, k-elems kstep*64..+63,
// at in-tile ush offset r*64 + ((sub16 ^ (r&7)) << 3) + (k&7), sub16=(k>>3)&7.
// Byte-identical to the GEMM's swizzled LDS image -> A-stage is a linear
// lane-contiguous global_load_lds copy; ds_read side unchanged.
//
// CACHE POLICY (R5/R6): GEMM outputs (wq, final out) are non-temporal so the
// 616MB streams never evict A/B working sets from L2/L3; producer kernels
// (LN, attn, out-proj) write cached so the next GEMM's single-pass A-read
// hits L3. Tile order is bx-fastest per XCD: A panel read ONCE (shared via
// XCD L2 by concurrent blocks), small B re-reads hit L3 (protected by NT).

// ---------- f32 -> bf16 convert (weights) ----------
__global__ __launch_bounds__(256) void conv_f32_bf16(const float* __restrict__ s,
                                                     unsigned short* __restrict__ d, int n4) {
  int i = blockIdx.x * 256 + threadIdx.x;
  if (i >= n4) return;
  f32x4 f = ((const f32x4*)s)[i];
  us4 u;
  u[0] = f2bf(f[0]); u[1] = f2bf(f[1]); u[2] = f2bf(f[2]); u[3] = f2bf(f[3]);
  ((us4*)d)[i] = u;
}

// ---------- LayerNorm: NT-read permuted fp32 row, write blocked-A bf16 ----------
__global__ __launch_bounds__(256) void ln_kernel(const float* __restrict__ src,
                                                 const float* __restrict__ w,
                                                 const float* __restrict__ b,
                                                 unsigned short* __restrict__ dst) {
  const int wv = threadIdx.x >> 6;
  const int lane = threadIdx.x & 63;
  const int n = blockIdx.x * 4 + wv;            // token row 0..100351
  const int bp = n >> 2, v = n & 3;
  const int bb = bp / 784, p = bp - bb * 784;
  const float* row = src + ((size_t)bb * 3136 + (size_t)v * 784 + p) * 768;
  f32x4 x0 = __builtin_nontemporal_load((const f32x4*)row + lane);
  f32x4 x1 = __builtin_nontemporal_load((const f32x4*)row + lane + 64);
  f32x4 x2 = __builtin_nontemporal_load((const f32x4*)row + lane + 128);
  float s  = x0[0] + x0[1] + x0[2] + x0[3] + x1[0] + x1[1] + x1[2] + x1[3]
           + x2[0] + x2[1] + x2[2] + x2[3];
  float ss = x0[0]*x0[0] + x0[1]*x0[1] + x0[2]*x0[2] + x0[3]*x0[3]
           + x1[0]*x1[0] + x1[1]*x1[1] + x1[2]*x1[2] + x1[3]*x1[3]
           + x2[0]*x2[0] + x2[1]*x2[1] + x2[2]*x2[2] + x2[3]*x2[3];
  #pragma unroll
  for (int off = 32; off > 0; off >>= 1) {
    s  += __shfl_xor(s,  off, 64);
    ss += __shfl_xor(ss, off, 64);
  }
  const float mu   = s * (1.0f / 768.0f);
  const float rstd = rsqrtf(ss * (1.0f / 768.0f) - mu * mu + 1e-5f);
  // blocked-A store: k = (lane + seg*64)*4 ; kstep=(lane>>4)+seg*4 ;
  // sub16=(lane>>1)&7 ; k&7=(lane&1)*4 ; r = n&255
  const int r = n & 255;
  unsigned short* bb2 = dst + (((size_t)(n >> 8) * 12) << 14) + r * 64
                      + ((((lane >> 1) & 7) ^ (r & 7)) << 3) + ((lane & 1) << 2);
  #pragma unroll
  for (int seg = 0; seg < 3; ++seg) {
    f32x4 xs = (seg == 0) ? x0 : (seg == 1) ? x1 : x2;
    f32x4 w4 = ((const f32x4*)w)[lane + seg * 64];
    f32x4 b4 = ((const f32x4*)b)[lane + seg * 64];
    us4 u;
    u[0] = f2bf((xs[0] - mu) * rstd * w4[0] + b4[0]);
    u[1] = f2bf((xs[1] - mu) * rstd * w4[1] + b4[1]);
    u[2] = f2bf((xs[2] - mu) * rstd * w4[2] + b4[2]);
    u[3] = f2bf((xs[3] - mu) * rstd * w4[3] + b4[3]);
    *(us4*)(bb2 + (((size_t)((lane >> 4) + seg * 4)) << 14)) = u;
  }
}

// =====================================================================
// GEMM: C = A(blocked bf16, MxK) * B(bf16, NxK)^T + epilogue
// 256x256 tile, BK=64, 8 waves (2M x 4N), 16x16x32 bf16 MFMA,
// 8-phase counted-vmcnt schedule, XOR-swizzled LDS (conflict-free b128).
// Tile order: bx-fastest within each XCD's by-band -> A panel read once
// (shared through XCD L2), B panels re-read from L3 (NT stores protect).
// =====================================================================

#define BARX() do { asm volatile("" ::: "memory"); \
                    __builtin_amdgcn_s_barrier();  \
                    asm volatile("" ::: "memory"); } while (0)
#define WAITVM(N) asm volatile("s_waitcnt vmcnt(" #N ")" ::: "memory")

// stage one 128-row half (16 KiB) of blocked A tile TT (linear copy)
#define STAGE_A(HALF, TT) do {                                                \
  _Pragma("unroll")                                                           \
  for (int _j = 0; _j < 2; ++_j) {                                            \
    const int _ob = ((HALF) << 13) + (w << 10) + (_j << 9);                   \
    __builtin_amdgcn_global_load_lds(                                         \
        (const __attribute__((address_space(1))) void*)(                      \
            gAt + (((size_t)(TT)) << 14) + _ob + lnoff8),                     \
        (__attribute__((address_space(3))) void*)(                            \
            smem + ((((TT) & 1)) << 15) + _ob), 16, 0, 0);                    \
  }                                                                           \
} while (0)

// stage one 128-row half (16 KiB) of B for K-step TT (pre-swizzled source)
#define STAGE_B(HALF, TT) do {                                                \
  const int _l0 = ((((TT) & 1)) << 15) + 16384 + ((HALF) << 13) + (w << 9);   \
  const ush* _g = gB + (size_t)(((HALF) << 7) + (w << 3)) * K                 \
                + (((size_t)(TT)) << 6);                                      \
  __builtin_amdgcn_global_load_lds(                                           \
      (const __attribute__((address_space(1))) void*)_g,                      \
      (__attribute__((address_space(3))) void*)(smem + _l0), 16, 0, 0);       \
  __builtin_amdgcn_global_load_lds(                                           \
      (const __attribute__((address_space(1))) void*)(_g + ((size_t)K << 6)), \
      (__attribute__((address_space(3))) void*)(smem + _l0 + 4096), 16, 0, 0);\
} while (0)

#define LDA(HM) do {                                                          \
  _Pragma("unroll")                                                           \
  for (int mi4 = 0; mi4 < 4; ++mi4) {                                         \
    const int m = wm * 64 + (HM) * 128 + mi4 * 16 + l16;                      \
    _Pragma("unroll")                                                         \
    for (int kk = 0; kk < 2; ++kk) {                                          \
      const int q = kk * 4 + quad;                                            \
      af[mi4][kk] = *(const bf16x8*)(smem + aofs + m * 64 + ((q ^ (m & 7)) << 3)); \
    }                                                                         \
  }                                                                           \
} while (0)

#define LDB(HN, BF) do {                                                      \
  _Pragma("unroll")                                                           \
  for (int ni2 = 0; ni2 < 2; ++ni2) {                                         \
    const int n = wn * 32 + (HN) * 128 + ni2 * 16 + l16;                      \
    _Pragma("unroll")                                                         \
    for (int kk = 0; kk < 2; ++kk) {                                          \
      const int q = kk * 4 + quad;                                            \
      BF[ni2][kk] = *(const bf16x8*)(smem + bofs + n * 64 + ((q ^ (n & 7)) << 3)); \
    }                                                                         \
  }                                                                           \
} while (0)

#define MFMAC(HM, HN, BF) do {                                                \
  __builtin_amdgcn_s_setprio(1);                                              \
  _Pragma("unroll")                                                           \
  for (int mi4 = 0; mi4 < 4; ++mi4)                                           \
    _Pragma("unroll")                                                         \
    for (int ni2 = 0; ni2 < 2; ++ni2)                                         \
      _Pragma("unroll")                                                       \
      for (int kk = 0; kk < 2; ++kk)                                          \
        acc[(HM)*4 + mi4][(HN)*2 + ni2] = __builtin_amdgcn_mfma_f32_16x16x32_bf16( \
            af[mi4][kk], BF[ni2][kk], acc[(HM)*4 + mi4][(HN)*2 + ni2], 0, 0, 0); \
  __builtin_amdgcn_s_setprio(0);                                              \
} while (0)

// EPI: 0 = +bias -> qkv bf16 [bp][seg][h][v][96]            (NT store)
//      1 = +bias +aux(NT) residual -> fp32 unfolded          (cached store)
//      2 = +bias, gelu -> bf16 blocked-A layout (NT=48)      (NT store)
//      3 = +bias +aux residual -> fp32 unfolded              (NT store)
template <int K, int EPI>
__global__ __launch_bounds__(512, 2) void gemm256(const ush* __restrict__ A,
                                                  const ush* __restrict__ Bm,
                                                  const float* __restrict__ bias,
                                                  void* __restrict__ outp,
                                                  const float* __restrict__ aux,
                                                  int N) {
  __shared__ __attribute__((aligned(16))) ush smem[65536];   // 128 KiB
  constexpr int NT = K / 64;
  const int tid  = threadIdx.x;
  const int w    = tid >> 6;
  const int lane = tid & 63;
  const int quad = lane >> 4;
  const int l16  = lane & 15;
  const int wm   = w >> 2;        // 0..1
  const int wn   = w & 3;         // 0..3

  // XCD-aware bijective remap: each XCD owns nwg/8 consecutive (by,bx) in
  // bx-fastest order -> A row-panel read once, shared through the XCD's L2.
  const int gx   = gridDim.x;
  const int nwg  = gx * 392;
  const int flat = blockIdx.y * gx + blockIdx.x;
  const int xcd  = flat & 7;
  const int pos  = xcd * (nwg >> 3) + (flat >> 3);
  const int by   = pos / gx;
  const int bx   = pos - by * gx;

  // A: blocked-tile base for this row-panel; lane-contiguous 16B pieces
  const ush* gAt   = A + (((size_t)by * NT) << 14);
  const int  lnoff8 = lane << 3;                 // lane*16B in ush

  // B: pre-swizzled per-lane global source (chunk cb loads chunk cb^r8)
  const int r8  = lane >> 3;
  const int cb  = lane & 7;
  const int swo = (cb ^ r8) << 3;
  const ush* gB = Bm + (size_t)(bx * 256 + r8) * K + swo;

  f32x4 acc[8][4];
  #pragma unroll
  for (int i = 0; i < 8; ++i)
    #pragma unroll
    for (int j = 0; j < 4; ++j) {
      f32x4 z = {0.0f, 0.0f, 0.0f, 0.0f};
      acc[i][j] = z;
    }
  bf16x8 af[4][2], bf0[2][2], bf1[2][2];

  // ---- prologue: stage halves A0,B0,A1,B1(t0), A0,B0(t1) ----
  STAGE_A(0, 0); STAGE_B(0, 0); STAGE_A(1, 0);
  STAGE_B(1, 0); STAGE_A(0, 1); STAGE_B(0, 1);
  WAITVM(8);              // A0(0),B0(0) landed (4 newest halves may fly)
  BARX();

  #pragma unroll 2
  for (int t = 0; t < NT; ++t) {
    const int aofs = (t & 1) << 15;
    const int bofs = aofs + 16384;
    // ---- q0: hm=0, hn=0 ----
    LDA(0); LDB(0, bf0);
    if (t <= NT - 2) STAGE_A(1, t + 1);      // A1(t+1) -> other buf
    BARX();
    MFMAC(0, 0, bf0);
    if (t < NT - 1) { WAITVM(6); } else { WAITVM(0); }  // A1(t),B1(t) landed
    BARX();
    // ---- q1: hm=0, hn=1 ----
    LDB(1, bf1);
    if (t <= NT - 2) STAGE_B(1, t + 1);      // B1(t+1) -> other buf
    BARX();
    MFMAC(0, 1, bf1);
    BARX();
    // ---- q2: hm=1, hn=0 ----
    LDA(1);
    if (t <= NT - 3) STAGE_A(0, t + 2);      // A0(t+2) -> this buf (half0 free)
    BARX();
    MFMAC(1, 0, bf0);
    BARX();
    // ---- q3: hm=1, hn=1 (B frags reused, no ds_reads) ----
    if (t <= NT - 3) STAGE_B(0, t + 2);      // B0(t+2) -> this buf (half0 free)
    BARX();
    MFMAC(1, 1, bf1);
    if (t <= NT - 3)      { WAITVM(8); }     // A0,B0(t+1) landed
    else if (t == NT - 2) { WAITVM(4); }
    BARX();
  }

  // ---- epilogue: 4 stages of 64 rows x 256 cols via LDS (stride 260) ----
  float* lsm = (float*)smem;
  #pragma unroll
  for (int s = 0; s < 4; ++s) {
    if (wm == (s & 1)) {
      const int hm = s >> 1;                 // compile-time (s unrolled)
      #pragma unroll
      for (int mi4 = 0; mi4 < 4; ++mi4)
        #pragma unroll
        for (int ni = 0; ni < 4; ++ni) {
          const int col = wn * 32 + (ni >> 1) * 128 + (ni & 1) * 16 + l16;
          #pragma unroll
          for (int r2 = 0; r2 < 4; ++r2) {
            const int row_l = mi4 * 16 + quad * 4 + r2;
            lsm[row_l * 260 + col] = acc[hm * 4 + mi4][ni][r2];
          }
        }
    }
    __syncthreads();
    #pragma unroll
    for (int j = 0; j < 8; ++j) {
      const int cc    = tid + 512 * j;       // 0..4095 = 64 rows x 64 chunks
      const int row_l = cc >> 6;
      const int c4    = (cc & 63) << 2;
      f32x4 vv = *(const f32x4*)&lsm[row_l * 260 + c4];
      const int rr    = by * 256 + s * 64 + row_l;
      const int col_g = bx * 256 + c4;
      f32x4 b4 = *(const f32x4*)&bias[col_g];
      vv += b4;
      if (EPI == 0) {
        const int seg = col_g / 768;
        const int c2  = col_g - seg * 768;
        const int hh  = c2 / 96;
        const int dd  = c2 - hh * 96;
        const int bp = rr >> 2, v = rr & 3;
        us4 u = { f2bf(vv[0]), f2bf(vv[1]), f2bf(vv[2]), f2bf(vv[3]) };
        __builtin_nontemporal_store(u,
            (us4*)((unsigned short*)outp + (size_t)bp * 9216 + seg * 3072 + hh * 384 + v * 96 + dd));
      } else if (EPI == 1 || EPI == 3) {
        const int bp = rr >> 2, v = rr & 3;
        const int bb = bp / 784, p2 = bp - bb * 784;
        const size_t addr = ((size_t)bb * 3136 + (size_t)v * 784 + p2) * 768 + col_g;
        f32x4 a4;
        if (EPI == 1) a4 = __builtin_nontemporal_load((const f32x4*)(aux + addr));
        else          a4 = *(const f32x4*)(aux + addr);
        vv += a4;
        if (EPI == 1) *(f32x4*)((float*)outp + addr) = vv;       // cached: LN2/FFN2 re-read
        else __builtin_nontemporal_store(vv, (f32x4*)((float*)outp + addr));
      } else { // EPI == 2: gelu -> bf16, blocked-A layout (NT=48) for FFN2
        us4 u = { f2bf(gelu_t(vv[0])), f2bf(gelu_t(vv[1])),
                  f2bf(gelu_t(vv[2])), f2bf(gelu_t(vv[3])) };
        const int rb = rr & 255;
        __builtin_nontemporal_store(u,
            (us4*)((unsigned short*)outp
               + (((size_t)(rr >> 8) * 48 + (col_g >> 6)) << 14)
               + rb * 64 + ((((col_g >> 3) & 7) ^ (rb & 7)) << 3) + (col_g & 7)));
      }
    }
    __syncthreads();
  }
}

// ---------- tiny cross-view attention: one thread per (bp, head, vq) ----------
// output: blocked-A layout (NT=12) for the out-proj GEMM
__global__ __launch_bounds__(256) void attn_kernel(const unsigned short* __restrict__ qs,
                                                   unsigned short* __restrict__ o) {
  int idx = blockIdx.x * 256 + threadIdx.x;   // 25088*32 total
  int vq = idx & 3;
  int h  = (idx >> 2) & 7;
  int bp = idx >> 5;
  const unsigned short* qp = qs + (size_t)bp * 9216 + h * 384 + vq * 96;
  const unsigned short* kp = qs + (size_t)bp * 9216 + 3072 + h * 384;
  const unsigned short* vp = qs + (size_t)bp * 9216 + 6144 + h * 384;
  float s0 = 0.f, s1 = 0.f, s2 = 0.f, s3 = 0.f;
  #pragma unroll
  for (int c = 0; c < 96; c += 8) {
    us8 q8 = __builtin_nontemporal_load((const us8*)(qp + c));
    us8 k0 = __builtin_nontemporal_load((const us8*)(kp + c));
    us8 k1 = __builtin_nontemporal_load((const us8*)(kp + 96 + c));
    us8 k2 = __builtin_nontemporal_load((const us8*)(kp + 192 + c));
    us8 k3 = __builtin_nontemporal_load((const us8*)(kp + 288 + c));
    #pragma unroll
    for (int j = 0; j < 8; ++j) {
      float qf = bf2f(q8[j]);
      s0 += qf * bf2f(k0[j]);
      s1 += qf * bf2f(k1[j]);
      s2 += qf * bf2f(k2[j]);
      s3 += qf * bf2f(k3[j]);
    }
  }
  const float scale = 0.10206207261596575f;  // 1/sqrt(96)
  s0 *= scale; s1 *= scale; s2 *= scale; s3 *= scale;
  float m = fmaxf(fmaxf(s0, s1), fmaxf(s2, s3));
  float e0 = __expf(s0 - m), e1 = __expf(s1 - m), e2 = __expf(s2 - m), e3 = __expf(s3 - m);
  float inv = 1.0f / (e0 + e1 + e2 + e3);
  e0 *= inv; e1 *= inv; e2 *= inv; e3 *= inv;
  const int rn = bp * 4 + vq;
  const int rr2 = rn & 255;
  unsigned short* ob = o + (((size_t)(rn >> 8) * 12) << 14) + rr2 * 64;
  #pragma unroll
  for (int c = 0; c < 96; c += 8) {
    us8 v0 = __builtin_nontemporal_load((const us8*)(vp + c));
    us8 v1 = __builtin_nontemporal_load((const us8*)(vp + 96 + c));
    us8 v2 = __builtin_nontemporal_load((const us8*)(vp + 192 + c));
    us8 v3 = __builtin_nontemporal_load((const us8*)(vp + 288 + c));
    us8 r;
    #pragma unroll
    for (int j = 0; j < 8; ++j) {
      float val = e0 * bf2f(v0[j]) + e1 * bf2f(v1[j]) + e2 * bf2f(v2[j]) + e3 * bf2f(v3[j]);
      r[j] = f2bf(val);
    }
    const int k = h * 96 + c;
    *(us8*)(ob + (((size_t)(k >> 6)) << 14) + ((((k >> 3) & 7) ^ (rr2 & 7)) << 3)) = r;
  }
}

// ---------- launch ----------
extern "C" void kernel_launch(void* const* d_in, const int* in_sizes, int n_in,
                              void* d_out, int out_size, void* d_ws, size_t ws_size,
                              hipStream_t stream) {
  const float* x         = (const float*)d_in[0];
  const float* norm1_w   = (const float*)d_in[2];
  const float* norm1_b   = (const float*)d_in[3];
  const float* in_proj_w = (const float*)d_in[4];
  const float* in_proj_b = (const float*)d_in[5];
  const float* out_w     = (const float*)d_in[6];
  const float* out_b     = (const float*)d_in[7];
  const float* norm2_w   = (const float*)d_in[8];
  const float* norm2_b   = (const float*)d_in[9];
  const float* ffn_w1    = (const float*)d_in[10];
  const float* ffn_b1    = (const float*)d_in[11];
  const float* ffn_w2    = (const float*)d_in[12];
  const float* ffn_b2    = (const float*)d_in[13];
  float* out = (float*)d_out;

  char* ws = (char*)d_ws;
  unsigned short* wq = (unsigned short*)ws;                           // 616.6 MB
  unsigned short* wh = (unsigned short*)(ws + 616562688u);            // 154.1 MB
  unsigned short* wB = (unsigned short*)(ws + 616562688u + 154140672u);
  unsigned short* wIn  = wB;
  unsigned short* wOut = wB + 1769472;
  unsigned short* wF1  = wOut + 589824;
  unsigned short* wF2  = wF1 + 2359296;

  conv_f32_bf16<<<(442368 + 255) / 256, 256, 0, stream>>>(in_proj_w, wIn, 442368);
  conv_f32_bf16<<<(147456 + 255) / 256, 256, 0, stream>>>(out_w, wOut, 147456);
  conv_f32_bf16<<<(589824 + 255) / 256, 256, 0, stream>>>(ffn_w1, wF1, 589824);
  conv_f32_bf16<<<(589824 + 255) / 256, 256, 0, stream>>>(ffn_w2, wF2, 589824);

  // LN1: x (NT permuted read) -> wh (blocked-A, NT=12; cached -> L3 for QKV)
  ln_kernel<<<25088, 256, 0, stream>>>(x, norm1_w, norm1_b, wh);
  // QKV: wh(100352x768) @ in_proj_w^T -> wq (attention layout, NT store)
  gemm256<768, 0><<<dim3(9, 392), 512, 0, stream>>>(wh, wIn, in_proj_b, (void*)wq, nullptr, 2304);
  // attention: wq (NT read) -> wh (o, blocked-A NT=12; cached)
  attn_kernel<<<3136, 256, 0, stream>>>(wq, wh);
  // out-proj + residual(x NT): wh @ out_w^T -> d_out fp32 (cached; LN2/FFN2 re-read)
  gemm256<768, 1><<<dim3(3, 392), 512, 0, stream>>>(wh, wOut, out_b, (void*)out, x, 768);
  // LN2: d_out (permuted read, L3-hot) -> wh (blocked-A, NT=12)
  ln_kernel<<<25088, 256, 0, stream>>>(out, norm2_w, norm2_b, wh);
  // FFN1 + gelu: wh @ ffn_w1^T -> wq (blocked-A, NT=48; NT store)
  gemm256<768, 2><<<dim3(12, 392), 512, 0, stream>>>(wh, wF1, ffn_b1, (void*)wq, nullptr, 3072);
  // FFN2 + residual(d_out): wq(blocked) @ ffn_w2^T -> d_out fp32 (NT store)
  gemm256<3072, 3><<<dim3(3, 392), 512, 0, stream>>>(wq, wF2, ffn_b2, (void*)out, out, 768);

  (void)in_sizes; (void)n_in; (void)out_size; (void)ws_size;
}